// Round 5
// baseline (136.975 us; speedup 1.0000x reference)
//
#include <hip/hip_runtime.h>
#include <stdint.h>

// SpottingLoss: B=2048 batches, N=64 slots, F=19 features.
// Two-phase greedy bipartite matching (lax.scan, length 64 each) then
// permuted YOLO-ish loss summed over ALL axes -> single float output.
//
// Exactness argument (verified absmax 0.0 in rounds 0-4):
//  - alpha in {0.0,1.0}; v,h stay exactly {0.0,1.0}; D2 = D1 * (0/1 factors),
//    so masking D1 (fp32, 1 - |x-p|, bit-identical) by the current
//    column-active bitmask reproduces D2 values bitwise.
//  - jnp.argmax ties -> first index. Row scan uses strict '>' over masked
//    values. Column argmax uses packed key (val_bits<<6 | (63-row)):
//    monotone in val (val>0), larger 63-row == smaller row == first index.
//  - No-reset key protocol (validated in round 1): every proposed column is
//    killed the same round and never proposed again; a live column at round
//    start has never been written, so its key is still the init value 63
//    (val=0,row=0). Stale keys on killed columns only re-assert colkill,
//    and hbits &= ~killed is idempotent. One init per batch covers both
//    phases (phase-1 proposals only target never-killed = never-written
//    columns).
//  - Dead rows (v=0) only contribute zeros downstream; early exit when
//    ballot(v)==0: all remaining scan steps are no-ops (E==0).
//  - Wave-local WSYNC (s_waitcnt lgkmcnt(0)) replaces __syncthreads
//    (validated round 4): all sync consumers are this wave's own ds ops;
//    DS ops of one wave are processed in issue order.
//
// Round-5 change: rounds 0-4 proved the wall (51-55us) is invariant to VALU
// work, atomics, global access pattern, and WG count -- but wave count was
// always 2048, and wall/waves = 25.4 ns/wave (39.4 waves/us) across ALL
// versions. Composed model: wall = max(wave-arrival ramp 52us, wave life
// ~20us); avg resident 39.4*21/256 = 3.2/CU matches measured 10% occupancy.
// Mechanism test: halve the wave count. Each wave processes KB=2 batches
// sequentially (1024 waves, 256 WGs x 4 waves). Also slim the per-round
// protocol (no reset write, 2 lgkm drains instead of 3) so the serial term
// 2 x T_batch stays below the new ~26us arrival ramp.

#define NN 64
#define NF 19
#define NW (NN * NF)   // 1216 floats per (batch, tensor)
#define NW4 (NW / 4)   // 304 float4
#define WPB 4          // waves per workgroup
#define KB  2          // batches per wave (sequential)
typedef unsigned long long u64;

// Wave-local LDS ordering: prior ds ops (writes/atomics) by this wave are
// complete and visible to this wave's subsequent ds reads.
#define WSYNC() asm volatile("s_waitcnt lgkmcnt(0)" ::: "memory")

__global__ __launch_bounds__(WPB * 64) void spotting_loss_kernel(
    const float* __restrict__ yt, const float* __restrict__ yp,
    float* __restrict__ ws, int nbatch)
{
  const int wid = threadIdx.x >> 6;   // wave id in block
  const int i   = threadIdx.x & 63;   // lane = row index
  const int g   = blockIdx.x * WPB + wid;  // global wave id

  __shared__ float4 yts4[WPB][NW4];
  __shared__ float4 yps4[WPB][NW4];
  __shared__ u64 key_lds[WPB][NN];
  const float* __restrict__ yts = (const float*)&yts4[wid][0];
  const float* __restrict__ yps = (const float*)&yps4[wid][0];
  u64* __restrict__ key_sh = &key_lds[wid][0];

  float lsum = 0.0f;

#pragma unroll 1
  for (int q = 0; q < KB; ++q) {
    const int b = g * KB + q;
    if (b >= nbatch) break;

    const float4* __restrict__ yt4 = (const float4*)(yt + (size_t)b * NW);
    const float4* __restrict__ yp4 = (const float4*)(yp + (size_t)b * NW);

    // Coalesced staging into this wave's private slice: 2 x 5 float4 loads.
#pragma unroll
    for (int k = 0; k < 5; ++k) {
      const int idx = i + 64 * k;     // 304 = 4*64 + 48
      if (idx < NW4) {
        yts4[wid][idx] = yt4[idx];
        yps4[wid][idx] = yp4[idx];
      }
    }
    key_sh[i] = 63ull;  // once per batch: (val=0,row=0) baseline
    WSYNC();

    const float alpha = yts[i * NF + 0];
    const float x     = yts[i * NF + 1];

    // D1 row in registers; yps[j*19+1] is wave-uniform -> LDS broadcast.
    float D1r[NN];
#pragma unroll
    for (int j = 0; j < NN; ++j) {
      D1r[j] = 1.0f - fabsf(x - yps[j * NF + 1]);
    }

    u64   hbits = ~0ull;  // column j active <=> bit j set
    int   perm  = 0;      // matched column (argmax of zero row -> 0)
    int   jmax  = 0;
    float best  = 0.0f;

    for (int phase = 0; phase < 2; ++phase) {
      // phase 0: v0 = alpha ; phase 1: v0 = 1-alpha
      bool vlive  = (phase == 0) ? (alpha > 0.5f) : (alpha < 0.5f);
      bool rescan = vlive;

      for (int it = 0; it < NN; ++it) {
        if (__ballot(vlive) == 0ull) break;  // remaining steps are no-ops

        if (rescan) {
          // first-index argmax over D1 masked by active columns
          const unsigned hlo = (unsigned)hbits;
          const unsigned hhi = (unsigned)(hbits >> 32);
          best = -1.0f; jmax = 0;
#pragma unroll
          for (int j = 0; j < NN; ++j) {
            const unsigned bit = (j < 32) ? ((hlo >> j) & 1u)
                                          : ((hhi >> (j - 32)) & 1u);
            const unsigned msk = 0u - bit;  // 0xFFFFFFFF or 0
            const float t = __uint_as_float(__float_as_uint(D1r[j]) & msk);
            if (t > best) { best = t; jmax = j; }
          }
          rescan = false;
        }

        if (vlive && best > 0.0f) {
          const u64 key = (((u64)__float_as_uint(best)) << 6) |
                          (u64)(63 - i);
          atomicMax(&key_sh[jmax], key);
        }
        WSYNC();  // all lanes' atomics complete before the reads below

        const u64 kc = key_sh[i];     // my column's key (stale-kill ok)
        const u64 kw = key_sh[jmax];  // my target's key (valid: jmax was live)
        WSYNC();

        const bool colkill = (kc >> 6) != 0ull;
        const u64 killed = __ballot(colkill);

        if (vlive) {
          const int winner = 63 - (int)(kw & 63ull);
          if (winner == i) {          // mutual match: Permut[i][jmax] = 1
            perm  = jmax;
            vlive = false;
          } else if ((killed >> jmax) & 1ull) {
            rescan = true;            // favorite column taken by another row
          }
        }
        hbits &= ~killed;
        // no end-of-round sync: next round's first DS op (atomic) targets a
        // live (never-written) column; same-wave DS ops process in order.
      }
    }

    // ----- loss (all operands from LDS), accumulate per lane -----
    const float* __restrict__ ypr = yps + perm * NF;
    const float* __restrict__ ytr = yts + i * NF;
    const float a  = alpha;
    const float p0 = ypr[0];
    const float p1 = ypr[1];
    const float dx = x - p1;
    const float da = a - p0;
    float s2 = 0.0f;
#pragma unroll
    for (int f = 2; f < NF; ++f) {
      const float d = ytr[f] - ypr[f];
      s2 += d * d;
    }
    lsum += a * 5.0f * (dx * dx)
          + a * (da * da)
          + (1.0f - a) * 0.5f * (da * da)
          + a * s2;
    // next batch's key_sh init write cannot overtake this batch's reads:
    // same-wave DS ordering; staging WSYNC drains everything anyway.
  }

  // wave-64 reduction over accumulated partials, one store per wave
#pragma unroll
  for (int off = 32; off > 0; off >>= 1) lsum += __shfl_down(lsum, off);
  if (i == 0) ws[g] = lsum;
}

__global__ __launch_bounds__(256) void reduce_ws_kernel(
    const float* __restrict__ ws, float* __restrict__ out, int nb)
{
  const int t = threadIdx.x;
  float s = 0.0f;
  for (int j = t; j < nb; j += 256) s += ws[j];
  __shared__ float part[4];
#pragma unroll
  for (int off = 32; off > 0; off >>= 1) s += __shfl_down(s, off);
  if ((t & 63) == 0) part[t >> 6] = s;
  __syncthreads();
  if (t == 0) out[0] = part[0] + part[1] + part[2] + part[3];
}

extern "C" void kernel_launch(void* const* d_in, const int* in_sizes, int n_in,
                              void* d_out, int out_size, void* d_ws, size_t ws_size,
                              hipStream_t stream) {
  const float* yt = (const float*)d_in[0];
  const float* yp = (const float*)d_in[1];
  float* out = (float*)d_out;
  float* ws  = (float*)d_ws;
  const int B = in_sizes[0] / (NN * NF);
  const int nwaves = (B + KB - 1) / KB;
  const int nblk = (nwaves + WPB - 1) / WPB;

  // harness poisons d_out with 0xAA; out[0] is fully overwritten by the
  // reduce kernel. Zero any additional output slots (none expected).
  if (out_size > 1) {
    hipMemsetAsync(out, 0, sizeof(float) * (size_t)out_size, stream);
  }
  spotting_loss_kernel<<<nblk, WPB * 64, 0, stream>>>(yt, yp, ws, B);
  reduce_ws_kernel<<<1, 256, 0, stream>>>(ws, out, nwaves);
}

// Round 6
// 110.936 us; speedup vs baseline: 1.2347x; 1.2347x over previous
//
#include <hip/hip_runtime.h>
#include <stdint.h>

// SpottingLoss: B=2048 batches, N=64 slots, F=19 features.
// Two-phase greedy bipartite matching (lax.scan, length 64 each) then
// permuted YOLO-ish loss summed over ALL axes -> single float output.
//
// Exactness argument (verified absmax 0.0 in rounds 0-5):
//  - alpha in {0.0,1.0}; v,h stay exactly {0.0,1.0}; D2 = D1 * (0/1 factors),
//    so masking D1 (fp32, 1 - |x-p|, bit-identical) by the current
//    column-active bitmask reproduces D2 values bitwise.
//  - jnp.argmax ties -> first index. Row scan uses strict '>' over masked
//    values. Column argmax uses packed key (val_bits<<6 | (63-row)):
//    monotone in val (val>0), larger 63-row == smaller row == first index.
//  - No-reset key protocol (validated rounds 1/5): every proposed column is
//    killed the same round and never proposed again; a live column at round
//    start has never been written, so its key is still the init value 63
//    (val=0,row=0). Stale keys on killed columns only re-assert colkill,
//    and hbits &= ~killed is idempotent. One init per batch covers both
//    phases.
//  - Dead rows (v=0) only contribute zeros downstream; early exit when
//    ballot(v)==0: all remaining scan steps are no-ops (E==0).
//  - Wave-local WSYNC (s_waitcnt lgkmcnt(0)) replaces __syncthreads
//    (validated rounds 4/5): all sync consumers are this wave's own ds ops;
//    DS ops of one wave are processed in issue order.
//
// Round-6 change (single mechanism): rounds 0-5 isolated the wall to
// per-wave life ~25us/batch (solving R4/R5: ramp~27us + life~25us), ~95%
// stall, invariant to HBM/LDS/atomics/WG-shape. Cause found in VGPR_Count
// = 52-68 across ALL versions: D1r[64] (64 VGPRs by itself) was NEVER in
// registers -- __launch_bounds__ with no occupancy arg made the compiler
// target 8 waves/SIMD (~64 VGPR budget) and spill the array to scratch.
// Each rescan = 64 scratch VMEM loads feeding the serial max chain
// (~250cy L2-hit each, unpipelined) ~= 16k cyc/rescan, 3-4 rescans/wave
// ~= the 60k-cycle life. Explains every null: warm-replay-identical
// (scratch L2-resident), FETCH~=inputs (scratch hits L2), VALUBusy low.
// Fix: __launch_bounds__(256, 1) -> up to 512 VGPRs; ~110-160 VGPRs still
// gives 4 waves/SIMD = 16 waves/CU (2x what was ever resident).
// Verify in counters: VGPR_Count must jump to ~110-160.

#define NN 64
#define NF 19
#define NW (NN * NF)   // 1216 floats per (batch, tensor)
#define NW4 (NW / 4)   // 304 float4
#define WPB 4          // waves (=batches) per workgroup
typedef unsigned long long u64;

// Wave-local LDS ordering: prior ds ops (writes/atomics) by this wave are
// complete and visible to this wave's subsequent ds reads.
#define WSYNC() asm volatile("s_waitcnt lgkmcnt(0)" ::: "memory")

__global__ __launch_bounds__(WPB * 64, 1) void spotting_loss_kernel(
    const float* __restrict__ yt, const float* __restrict__ yp,
    float* __restrict__ ws, int nbatch)
{
  const int wid = threadIdx.x >> 6;   // wave id in block
  const int i   = threadIdx.x & 63;   // lane = row index
  const int b   = blockIdx.x * WPB + wid;
  if (b >= nbatch) return;            // no block-wide sync anywhere

  const float4* __restrict__ yt4 = (const float4*)(yt + (size_t)b * NW);
  const float4* __restrict__ yp4 = (const float4*)(yp + (size_t)b * NW);

  __shared__ float4 yts4[WPB][NW4];
  __shared__ float4 yps4[WPB][NW4];
  __shared__ u64 key_lds[WPB][NN];
  const float* __restrict__ yts = (const float*)&yts4[wid][0];
  const float* __restrict__ yps = (const float*)&yps4[wid][0];
  u64* __restrict__ key_sh = &key_lds[wid][0];

  // Coalesced staging into this wave's private slice: 2 x 5 float4 loads.
#pragma unroll
  for (int k = 0; k < 5; ++k) {
    const int idx = i + 64 * k;       // 304 = 4*64 + 48
    if (idx < NW4) {
      yts4[wid][idx] = yt4[idx];
      yps4[wid][idx] = yp4[idx];
    }
  }
  key_sh[i] = 63ull;  // once per batch: (val=0,row=0) baseline, never reset
  WSYNC();

  const float alpha = yts[i * NF + 0];
  const float x     = yts[i * NF + 1];

  // D1 row in registers (the point of this round: VGPR budget now allows it).
  float D1r[NN];
#pragma unroll
  for (int j = 0; j < NN; ++j) {
    D1r[j] = 1.0f - fabsf(x - yps[j * NF + 1]);
  }

  u64   hbits = ~0ull;  // column j active <=> bit j set
  int   perm  = 0;      // matched column (argmax of zero row -> 0)
  int   jmax  = 0;
  float best  = 0.0f;

  for (int phase = 0; phase < 2; ++phase) {
    // phase 0: v0 = alpha ; phase 1: v0 = 1-alpha (neg rows untouched by ph.0)
    bool vlive  = (phase == 0) ? (alpha > 0.5f) : (alpha < 0.5f);
    bool rescan = vlive;

    for (int it = 0; it < NN; ++it) {
      if (__ballot(vlive) == 0ull) break;  // remaining steps are no-ops

      if (rescan) {
        // first-index argmax over D1 masked by active columns
        const unsigned hlo = (unsigned)hbits;
        const unsigned hhi = (unsigned)(hbits >> 32);
        best = -1.0f; jmax = 0;
#pragma unroll
        for (int j = 0; j < NN; ++j) {
          const unsigned bit = (j < 32) ? ((hlo >> j) & 1u)
                                        : ((hhi >> (j - 32)) & 1u);
          const unsigned msk = 0u - bit;  // 0xFFFFFFFF or 0
          const float t = __uint_as_float(__float_as_uint(D1r[j]) & msk);
          if (t > best) { best = t; jmax = j; }
        }
        rescan = false;
      }

      if (vlive && best > 0.0f) {
        const u64 key = (((u64)__float_as_uint(best)) << 6) |
                        (u64)(63 - i);
        atomicMax(&key_sh[jmax], key);
      }
      WSYNC();  // all lanes' atomics complete before the reads below

      const u64 kc = key_sh[i];     // my column's key (stale-kill ok)
      const u64 kw = key_sh[jmax];  // my target's key (valid while proposing)
      WSYNC();

      const bool colkill = (kc >> 6) != 0ull;
      const u64 killed = __ballot(colkill);

      if (vlive) {
        const int winner = 63 - (int)(kw & 63ull);
        if (winner == i) {          // mutual match: Permut[i][jmax] = 1
          perm  = jmax;
          vlive = false;
        } else if ((killed >> jmax) & 1ull) {
          rescan = true;            // favorite column taken by another row
        }
      }
      hbits &= ~killed;
      // no end-of-round sync needed: next round's first DS op (atomic)
      // targets a live (never-written) column; same-wave DS ops process
      // in issue order.
    }
  }

  // ----- loss (all operands from LDS) -----
  const float* __restrict__ ypr = yps + perm * NF;
  const float* __restrict__ ytr = yts + i * NF;
  const float a  = alpha;
  const float p0 = ypr[0];
  const float p1 = ypr[1];
  const float dx = x - p1;
  const float da = a - p0;
  float s2 = 0.0f;
#pragma unroll
  for (int f = 2; f < NF; ++f) {
    const float d = ytr[f] - ypr[f];
    s2 += d * d;
  }
  float l = a * 5.0f * (dx * dx)
          + a * (da * da)
          + (1.0f - a) * 0.5f * (da * da)
          + a * s2;

  // wave-64 reduction, one plain store per wave (no atomic contention)
#pragma unroll
  for (int off = 32; off > 0; off >>= 1) l += __shfl_down(l, off);
  if (i == 0) ws[b] = l;
}

__global__ __launch_bounds__(256) void reduce_ws_kernel(
    const float* __restrict__ ws, float* __restrict__ out, int nb)
{
  const int t = threadIdx.x;
  float s = 0.0f;
  for (int j = t; j < nb; j += 256) s += ws[j];
  __shared__ float part[4];
#pragma unroll
  for (int off = 32; off > 0; off >>= 1) s += __shfl_down(s, off);
  if ((t & 63) == 0) part[t >> 6] = s;
  __syncthreads();
  if (t == 0) out[0] = part[0] + part[1] + part[2] + part[3];
}

extern "C" void kernel_launch(void* const* d_in, const int* in_sizes, int n_in,
                              void* d_out, int out_size, void* d_ws, size_t ws_size,
                              hipStream_t stream) {
  const float* yt = (const float*)d_in[0];
  const float* yp = (const float*)d_in[1];
  float* out = (float*)d_out;
  float* ws  = (float*)d_ws;
  const int B = in_sizes[0] / (NN * NF);
  const int nblk = (B + WPB - 1) / WPB;

  // harness poisons d_out with 0xAA; out[0] is fully overwritten by the
  // reduce kernel. Zero any additional output slots (none expected).
  if (out_size > 1) {
    hipMemsetAsync(out, 0, sizeof(float) * (size_t)out_size, stream);
  }
  spotting_loss_kernel<<<nblk, WPB * 64, 0, stream>>>(yt, yp, ws, B);
  reduce_ws_kernel<<<1, 256, 0, stream>>>(ws, out, B);
}